// Round 7
// baseline (1334.309 us; speedup 1.0000x reference)
//
#include <hip/hip_runtime.h>

// 2-layer hetero SAGEConv, fully global-atomic-free:
//   radix partition by dst-bucket (LDS histograms) -> per-bucket local CSR
//   (LDS scan/rank) -> wave-per-node gather-mean -> two fused tile-GEMMs
//   with in-tile second stage (@Wl2 var path, @Wr2+bl2 config path).
//  - (msum/cnt)@W == (msum@W)/cnt
//  - h_var and h_config never materialized in global memory.
//  - Fb LDS uses a (col4 + row/4)&15 rotate swizzle: k-strided writes
//    conflict-free; k-loop reads are quarter-wave broadcasts.
//  - GEMM variants kept as SEPARATE kernels: merging them into one kernel
//    (round 6) made regalloc provision for both unrolled paths -> 256 VGPR
//    + scratch spills (1.4 GB/launch of HBM spill traffic).
//  - to_dense_batch is an identity reshape (batch = arange(NC)//K).

#define CHUNK 4096      // edges per partition block
#define EPT 16          // edges per thread (CHUNK/256)
#define MAXBINS 1024

// ---- partition phase 1: counts[bin][block], no global atomics ----
__global__ __launch_bounds__(256) void part_count2_kernel(
    const int* __restrict__ dstC, const int* __restrict__ dstV, int E, int nblocks,
    int nbinsC, int nbinsV, int* __restrict__ countsC, int* __restrict__ countsV) {
    const int* dst; int shift, nbins; int* counts; int b;
    if (blockIdx.x < (unsigned)nblocks) { dst = dstC; shift = 6; nbins = nbinsC; counts = countsC; b = blockIdx.x; }
    else { dst = dstV; shift = 7; nbins = nbinsV; counts = countsV; b = blockIdx.x - nblocks; }
    __shared__ int hist[MAXBINS];
    int t = threadIdx.x;
    for (int j = t; j < nbins; j += 256) hist[j] = 0;
    __syncthreads();
    int base = b * CHUNK;
#pragma unroll
    for (int j = 0; j < EPT; ++j) {
        int e = base + j * 256 + t;
        if (e < E) atomicAdd(&hist[dst[e] >> shift], 1);
    }
    __syncthreads();
    for (int j = t; j < nbins; j += 256) counts[(size_t)j * nblocks + b] = hist[j];
}

// ---- phase 2a: per-bin exclusive prefix over blocks; binTot ----
__global__ __launch_bounds__(256) void part_rowscan2_kernel(
    int* __restrict__ countsC, int nbinsC, int* __restrict__ binTotC,
    int* __restrict__ countsV, int* __restrict__ binTotV, int nblocks) {
    int* counts; int* binTot; int bin;
    if (blockIdx.x < (unsigned)nbinsC) { counts = countsC; binTot = binTotC; bin = blockIdx.x; }
    else { counts = countsV; binTot = binTotV; bin = blockIdx.x - nbinsC; }
    __shared__ int s[256];
    int t = threadIdx.x;
    int v = (t < nblocks) ? counts[(size_t)bin * nblocks + t] : 0;
    s[t] = v; __syncthreads();
    for (int o = 1; o < 256; o <<= 1) {
        int add = (t >= o) ? s[t - o] : 0; __syncthreads();
        s[t] += add; __syncthreads();
    }
    if (t < nblocks) counts[(size_t)bin * nblocks + t] = s[t] - v;
    if (t == nblocks - 1) binTot[bin] = s[t];
}

// ---- phase 2b: exclusive prefix over bins ----
__global__ __launch_bounds__(256) void part_binscan2_kernel(
    const int* __restrict__ binTotC, int nbinsC, int* __restrict__ binBaseC,
    const int* __restrict__ binTotV, int nbinsV, int* __restrict__ binBaseV) {
    const int* binTot; int nbins; int* binBase;
    if (blockIdx.x == 0) { binTot = binTotC; nbins = nbinsC; binBase = binBaseC; }
    else { binTot = binTotV; nbins = nbinsV; binBase = binBaseV; }
    __shared__ int s[256];
    __shared__ int carry;
    int t = threadIdx.x;
    if (t == 0) carry = 0;
    __syncthreads();
    for (int c0 = 0; c0 < nbins; c0 += 256) {
        int v = (c0 + t < nbins) ? binTot[c0 + t] : 0;
        s[t] = v; __syncthreads();
        for (int o = 1; o < 256; o <<= 1) {
            int add = (t >= o) ? s[t - o] : 0; __syncthreads();
            s[t] += add; __syncthreads();
        }
        if (c0 + t < nbins) binBase[c0 + t] = carry + s[t] - v;
        __syncthreads();
        if (t == 255) carry += s[255];
        __syncthreads();
    }
    if (t == 0) binBase[nbins] = carry;
}

// ---- phase 3: scatter packed (src<<shift)|local to deterministic slots ----
__global__ __launch_bounds__(256) void part_scatter2_kernel(
    const int* __restrict__ srcC, const int* __restrict__ dstC,
    const int* __restrict__ srcV, const int* __restrict__ dstV, int E, int nblocks,
    int nbinsC, const int* __restrict__ countsC, const int* __restrict__ binBaseC,
    int* __restrict__ ebufC,
    int nbinsV, const int* __restrict__ countsV, const int* __restrict__ binBaseV,
    int* __restrict__ ebufV) {
    const int *src, *dst, *counts, *binBase; int* ebuf; int shift, mask, nbins; int b;
    if (blockIdx.x < (unsigned)nblocks) {
        src = srcC; dst = dstC; counts = countsC; binBase = binBaseC; ebuf = ebufC;
        shift = 6; mask = 63; nbins = nbinsC; b = blockIdx.x;
    } else {
        src = srcV; dst = dstV; counts = countsV; binBase = binBaseV; ebuf = ebufV;
        shift = 7; mask = 127; nbins = nbinsV; b = blockIdx.x - nblocks;
    }
    __shared__ int hist[MAXBINS];
    int t = threadIdx.x;
    for (int j = t; j < nbins; j += 256) hist[j] = 0;
    __syncthreads();
    int base = b * CHUNK;
#pragma unroll
    for (int j = 0; j < EPT; ++j) {
        int e = base + j * 256 + t;
        if (e < E) {
            int d = dst[e];
            int bin = d >> shift;
            int rank = atomicAdd(&hist[bin], 1);
            int slot = binBase[bin] + counts[(size_t)bin * nblocks + b] + rank;
            ebuf[slot] = (src[e] << shift) | (d & mask);
        }
    }
}

// ---- phase 4: per-bucket local CSR (LDS only): ebuf2 per-node-ordered + off ----
__global__ __launch_bounds__(256) void csr2_kernel(
    int nbinsC, const int* __restrict__ binBaseC, const int* __restrict__ ebufC,
    int* __restrict__ ebufC2, int* __restrict__ offC, int nC,
    const int* __restrict__ binBaseV, const int* __restrict__ ebufV,
    int* __restrict__ ebufV2, int* __restrict__ offV, int nV, int E) {
    __shared__ int hist[128];
    __shared__ int cur[128];
    __shared__ int s[256];
    int t = threadIdx.x;
    const int *binBase, *eb1; int *eb2, *off; int n, shift, bin;
    if (blockIdx.x < (unsigned)nbinsC) {
        bin = blockIdx.x; binBase = binBaseC; eb1 = ebufC; eb2 = ebufC2; off = offC; n = nC; shift = 6;
    } else {
        bin = blockIdx.x - nbinsC; binBase = binBaseV; eb1 = ebufV; eb2 = ebufV2; off = offV; n = nV; shift = 7;
    }
    int mask = (1 << shift) - 1, nloc = 1 << shift;
    if (blockIdx.x == 0 && t == 0) { offC[nC] = E; offV[nV] = E; }
    int e0 = binBase[bin], e1 = binBase[bin + 1];
    if (t < nloc) { hist[t] = 0; cur[t] = 0; }
    __syncthreads();
    for (int e = e0 + t; e < e1; e += 256) atomicAdd(&hist[eb1[e] & mask], 1);
    __syncthreads();
    int v = (t < nloc) ? hist[t] : 0;
    s[t] = v; __syncthreads();
    for (int o = 1; o < 256; o <<= 1) {
        int add = (t >= o) ? s[t - o] : 0; __syncthreads();
        s[t] += add; __syncthreads();
    }
    if (t < nloc) {
        int node = (bin << shift) + t;
        if (node < n) off[node] = e0 + s[t] - v;
        hist[t] = s[t] - v;   // reuse as local exclusive offset
    }
    __syncthreads();
    for (int e = e0 + t; e < e1; e += 256) {
        int w = eb1[e];
        int local = w & mask;
        int r = atomicAdd(&cur[local], 1);
        eb2[e0 + hist[local] + r] = w >> shift;
    }
}

// ---- wave-per-node gather-mean bodies ----
__device__ __forceinline__ void gather64_body(
    const int* __restrict__ off, const int* __restrict__ eb,
    const float* __restrict__ X, float* __restrict__ M,
    const float* __restrict__ P, float* __restrict__ out,
    int n, int b, int nblocks) {
    int lane = threadIdx.x & 63, wid = threadIdx.x >> 6;
    int nw = nblocks * 4;
    for (int i = b * 4 + wid; i < n; i += nw) {
        int e0 = off[i], e1 = off[i + 1];
        int deg = e1 - e0;
        float acc = 0.f;
        for (int j0 = 0; j0 < deg; j0 += 64) {
            int m = min(deg - j0, 64);
            int idx = 0;
            if (lane < m) idx = eb[e0 + j0 + lane];
            int j = 0;
            for (; j + 4 <= m; j += 4) {
                int s0 = __shfl(idx, j);
                int s1 = __shfl(idx, j + 1);
                int s2 = __shfl(idx, j + 2);
                int s3 = __shfl(idx, j + 3);
                acc += X[(size_t)s0 * 64 + lane];
                acc += X[(size_t)s1 * 64 + lane];
                acc += X[(size_t)s2 * 64 + lane];
                acc += X[(size_t)s3 * 64 + lane];
            }
            for (; j < m; ++j) {
                int s = __shfl(idx, j);
                acc += X[(size_t)s * 64 + lane];
            }
        }
        float r = acc / fmaxf((float)deg, 1.0f);
        if (out) out[(size_t)i * 64 + lane] = r + P[(size_t)i * 64 + lane];
        else     M[(size_t)i * 64 + lane] = r;
    }
}

__device__ __forceinline__ void gather16_body(
    const int* __restrict__ off, const int* __restrict__ eb,
    const float* __restrict__ X, float* __restrict__ M, int n, int b, int nblocks) {
    int lane = threadIdx.x & 63, wid = threadIdx.x >> 6;
    int dlane = lane & 15, eg = lane >> 4;
    int nw = nblocks * 4;
    for (int i = b * 4 + wid; i < n; i += nw) {
        int e0 = off[i], e1 = off[i + 1];
        int deg = e1 - e0;
        float acc = 0.f;
        for (int j0 = 0; j0 < deg; j0 += 64) {
            int m = min(deg - j0, 64);
            int idx = 0;
            if (lane < m) idx = eb[e0 + j0 + lane];
            for (int j = eg; j < m; j += 4) {
                int s = __shfl(idx, j);
                acc += X[(size_t)s * 16 + dlane];
            }
        }
        acc += __shfl_xor(acc, 16);
        acc += __shfl_xor(acc, 32);
        if (lane < 16) M[(size_t)i * 16 + lane] = acc / fmaxf((float)deg, 1.0f);
    }
}

// combined layer-1 gathers (independent)
__global__ __launch_bounds__(256) void gather2_kernel(
    const int* __restrict__ offC, const int* __restrict__ ebC,
    const float* __restrict__ Xc, float* __restrict__ Mc, int nC, int gbC,
    const int* __restrict__ offV, const int* __restrict__ ebV,
    const float* __restrict__ Xv, float* __restrict__ Mv, int nV, int gbV) {
    if (blockIdx.x < (unsigned)gbC)
        gather64_body(offC, ebC, Xc, Mc, nullptr, nullptr, nC, blockIdx.x, gbC);
    else
        gather16_body(offV, ebV, Xv, Mv, nV, blockIdx.x - gbC, gbV);
}

// layer-2 gather fused with final add: out = mean(hv2) + OCp
__global__ __launch_bounds__(256) void gather64_add_kernel(
    const int* __restrict__ off, const int* __restrict__ eb,
    const float* __restrict__ X, const float* __restrict__ P,
    float* __restrict__ out, int n) {
    gather64_body(off, eb, X, nullptr, P, out, n, blockIdx.x, gridDim.x);
}

// ---------------- fused tile GEMM (swizzled LDS) ----------------
// Fb layout: 128 rows x 68 floats; float4 (row, col4) stored at
//   col4' = (col4 + (row>>2)) & 15  -> k-strided writes conflict-free,
//   k-loop reads stay quarter-wave broadcasts. Every access touches rows
//   4m..4m+3 with constant row>>2, so the swizzle index is uniform per access.
template<int D, int ROW0>
__device__ __forceinline__ void stageF_swz(const float* __restrict__ A, float* __restrict__ Fb,
                                           int i0, int n, int t) {
    const int Q = D / 4;          // float4s per input row
    const int NPP = 256 / Q;      // nodes per pass
#pragma unroll
    for (int p = 0; p < 64 / NPP; ++p) {
        int nn = t / Q + p * NPP;      // node 0..63
        int k4 = t % Q;                // input float4 index
        int node = i0 + nn;
        float4 v = make_float4(0.f, 0.f, 0.f, 0.f);
        if (node < n) v = ((const float4*)A)[(size_t)node * Q + k4];
        int cs = (((nn >> 2) + (ROW0 >> 2) + k4) & 15) * 4 + (nn & 3);
        float* q = Fb + (ROW0 + 4 * k4) * 68 + cs;
        q[0 * 68] = v.x; q[1 * 68] = v.y; q[2 * 68] = v.z; q[3 * 68] = v.w;
    }
}

// stage1: H[64n][128] = relu(M[:,D1]@Wl + X[:,D2]@Wr + bias) (kept in LDS)
// stage2: O[64n][64]  = H @ W2 (+ bias2 if HASB2)
template<int D1, int D2, bool HASB2>
__global__ __launch_bounds__(256) void gemm_swz_kernel(
    const float* __restrict__ M, const float* __restrict__ X,
    const float* __restrict__ Wl, const float* __restrict__ Wr,
    const float* __restrict__ bias, const float* __restrict__ W2,
    const float* __restrict__ bias2, float* __restrict__ O, int n) {
    __shared__ float Fb[128 * 68];
    __shared__ float Wb[80 * 128];
    int t = threadIdx.x;
    int i0 = blockIdx.x * 64;
    {
        const float4* wl4 = (const float4*)Wl;
        const float4* wr4 = (const float4*)Wr;
        float4* wb4 = (float4*)Wb;
        for (int j = t; j < D1 * 32; j += 256) wb4[j] = wl4[j];
        for (int j = t; j < D2 * 32; j += 256) wb4[D1 * 32 + j] = wr4[j];
    }
    stageF_swz<D1, 0>(M, Fb, i0, n, t);
    stageF_swz<D2, D1>(X, Fb, i0, n, t);
    __syncthreads();
    int tc = t & 15, tn = t >> 4;
    int c0 = tc * 4, n0 = tn * 4;
    float acc[4][8];
#pragma unroll
    for (int j = 0; j < 4; ++j)
#pragma unroll
        for (int jj = 0; jj < 8; ++jj) acc[j][jj] = 0.f;
#pragma unroll
    for (int kg = 0; kg < (D1 + D2) / 4; ++kg) {
        int sw = ((tn + kg) & 15) * 4;
#pragma unroll
        for (int j4 = 0; j4 < 4; ++j4) {
            int k = 4 * kg + j4;
            float4 f  = *(const float4*)&Fb[k * 68 + sw];
            float4 wa = *(const float4*)&Wb[k * 128 + c0];
            float4 wc = *(const float4*)&Wb[k * 128 + 64 + c0];
            float ff[4] = {f.x, f.y, f.z, f.w};
            float va[4] = {wa.x, wa.y, wa.z, wa.w};
            float vb[4] = {wc.x, wc.y, wc.z, wc.w};
#pragma unroll
            for (int j = 0; j < 4; ++j)
#pragma unroll
                for (int jj = 0; jj < 4; ++jj) {
                    acc[j][jj]     += ff[j] * va[jj];
                    acc[j][4 + jj] += ff[j] * vb[jj];
                }
        }
    }
    __syncthreads();   // all stage-1 reads of Fb/Wb done
    {
        float4 blo = ((const float4*)bias)[tc];
        float4 bhi = ((const float4*)bias)[16 + tc];
        float bl[8] = {blo.x, blo.y, blo.z, blo.w, bhi.x, bhi.y, bhi.z, bhi.w};
        int sw1 = ((tn + tc) & 15) * 4;        // rows c0+jj:    row>>2 = tc
        int sw2 = ((tn + 16 + tc) & 15) * 4;   // rows 64+c0+jj: row>>2 = 16+tc
#pragma unroll
        for (int jj = 0; jj < 4; ++jj) {
            float4 h1, h2;
            h1.x = fmaxf(acc[0][jj] + bl[jj], 0.f);
            h1.y = fmaxf(acc[1][jj] + bl[jj], 0.f);
            h1.z = fmaxf(acc[2][jj] + bl[jj], 0.f);
            h1.w = fmaxf(acc[3][jj] + bl[jj], 0.f);
            h2.x = fmaxf(acc[0][4 + jj] + bl[4 + jj], 0.f);
            h2.y = fmaxf(acc[1][4 + jj] + bl[4 + jj], 0.f);
            h2.z = fmaxf(acc[2][4 + jj] + bl[4 + jj], 0.f);
            h2.w = fmaxf(acc[3][4 + jj] + bl[4 + jj], 0.f);
            // H row = c0+jj (and 64+c0+jj), col4 = tn
            *(float4*)&Fb[(c0 + jj) * 68 + sw1] = h1;
            *(float4*)&Fb[(64 + c0 + jj) * 68 + sw2] = h2;
        }
        const float4* w24 = (const float4*)W2;
        float4* wb4 = (float4*)Wb;
        for (int j = t; j < 128 * 16; j += 256) wb4[j] = w24[j];
    }
    __syncthreads();
    float a2[4][4];
#pragma unroll
    for (int j = 0; j < 4; ++j)
#pragma unroll
        for (int jj = 0; jj < 4; ++jj) a2[j][jj] = 0.f;
#pragma unroll
    for (int kg = 0; kg < 32; ++kg) {
        int sw = ((tn + kg) & 15) * 4;
#pragma unroll
        for (int j4 = 0; j4 < 4; ++j4) {
            int k = 4 * kg + j4;
            float4 h = *(const float4*)&Fb[k * 68 + sw];
            float4 w = *(const float4*)&Wb[k * 64 + c0];
            float hh[4] = {h.x, h.y, h.z, h.w};
            float ww[4] = {w.x, w.y, w.z, w.w};
#pragma unroll
            for (int j = 0; j < 4; ++j)
#pragma unroll
                for (int jj = 0; jj < 4; ++jj) a2[j][jj] += hh[j] * ww[jj];
        }
    }
    float4 b2 = HASB2 ? ((const float4*)bias2)[tc] : make_float4(0.f, 0.f, 0.f, 0.f);
#pragma unroll
    for (int j = 0; j < 4; ++j) {
        int node = i0 + n0 + j;
        if (node < n) {
            float4 o = {a2[j][0] + b2.x, a2[j][1] + b2.y, a2[j][2] + b2.z, a2[j][3] + b2.w};
            ((float4*)O)[(size_t)node * 16 + tc] = o;
        }
    }
}

extern "C" void kernel_launch(void* const* d_in, const int* in_sizes, int n_in,
                              void* d_out, int out_size, void* d_ws, size_t ws_size,
                              hipStream_t stream) {
    const float* x_var    = (const float*)d_in[0];
    const float* x_config = (const float*)d_in[1];
    const int* src_v2c = (const int*)d_in[2];
    const int* dst_v2c = (const int*)d_in[3];
    const int* src_c2v = (const int*)d_in[4];
    const int* dst_c2v = (const int*)d_in[5];
    const float* Wl1_v2c = (const float*)d_in[7];
    const float* bl1_v2c = (const float*)d_in[8];
    const float* Wr1_v2c = (const float*)d_in[9];
    const float* Wl1_c2v = (const float*)d_in[10];
    const float* bl1_c2v = (const float*)d_in[11];
    const float* Wr1_c2v = (const float*)d_in[12];
    const float* Wl2 = (const float*)d_in[13];
    const float* bl2 = (const float*)d_in[14];
    const float* Wr2 = (const float*)d_in[15];
    float* out = (float*)d_out;

    int NV = in_sizes[0] / 64;
    int NC = in_sizes[1] / 16;
    int E  = in_sizes[2];

    int nblocks = (E + CHUNK - 1) / CHUNK;          // <=256 for rowscan
    int nbins_c = (NC + 63) >> 6;                   // 64 config nodes / bucket
    int nbins_v = (NV + 127) >> 7;                  // 128 var nodes / bucket

    char* p = (char*)d_ws;
    float* Mc  = (float*)p; p += (size_t)NC * 64 * 4;
    float* Mv  = (float*)p; p += (size_t)NV * 16 * 4;
    float* OCp = (float*)p; p += (size_t)NC * 64 * 4;   // h_config@Wr2 + bl2
    float* hv2 = (float*)p; p += (size_t)NV * 64 * 4;   // h_var@Wl2
    int* countsC = (int*)p; p += (size_t)nbins_c * nblocks * 4;
    int* countsV = (int*)p; p += (size_t)nbins_v * nblocks * 4;
    int* binTotC = (int*)p; p += (size_t)nbins_c * 4;
    int* binTotV = (int*)p; p += (size_t)nbins_v * 4;
    int* binBaseC = (int*)p; p += (size_t)(nbins_c + 1) * 4;
    int* binBaseV = (int*)p; p += (size_t)(nbins_v + 1) * 4;
    int* offC = (int*)p; p += (size_t)(NC + 1) * 4;
    int* offV = (int*)p; p += (size_t)(NV + 1) * 4;
    int* ebufC  = (int*)p; p += (size_t)E * 4;
    int* ebufV  = (int*)p; p += (size_t)E * 4;
    int* ebufC2 = (int*)p; p += (size_t)E * 4;
    int* ebufV2 = (int*)p; p += (size_t)E * 4;

    part_count2_kernel<<<2 * nblocks, 256, 0, stream>>>(
        dst_v2c, dst_c2v, E, nblocks, nbins_c, nbins_v, countsC, countsV);
    part_rowscan2_kernel<<<nbins_c + nbins_v, 256, 0, stream>>>(
        countsC, nbins_c, binTotC, countsV, binTotV, nblocks);
    part_binscan2_kernel<<<2, 256, 0, stream>>>(
        binTotC, nbins_c, binBaseC, binTotV, nbins_v, binBaseV);
    part_scatter2_kernel<<<2 * nblocks, 256, 0, stream>>>(
        src_v2c, dst_v2c, src_c2v, dst_c2v, E, nblocks,
        nbins_c, countsC, binBaseC, ebufC,
        nbins_v, countsV, binBaseV, ebufV);
    csr2_kernel<<<nbins_c + nbins_v, 256, 0, stream>>>(
        nbins_c, binBaseC, ebufC, ebufC2, offC, NC,
        binBaseV, ebufV, ebufV2, offV, NV, E);

    int gbC = (NC + 3) / 4, gbV = (NV + 3) / 4;
    gather2_kernel<<<gbC + gbV, 256, 0, stream>>>(
        offC, ebufC2, x_var, Mc, NC, gbC,
        offV, ebufV2, x_config, Mv, NV, gbV);

    gemm_swz_kernel<64, 16, true><<<(NC + 63) / 64, 256, 0, stream>>>(
        Mc, x_config, Wl1_v2c, Wr1_v2c, bl1_v2c, Wr2, bl2, OCp, NC);
    gemm_swz_kernel<16, 64, false><<<(NV + 63) / 64, 256, 0, stream>>>(
        Mv, x_var, Wl1_c2v, Wr1_c2v, bl1_c2v, Wl2, nullptr, hv2, NV);

    gather64_add_kernel<<<gbC, 256, 0, stream>>>(offC, ebufC2, hv2, OCp, out, NC);
}

// Round 8
// 338.060 us; speedup vs baseline: 3.9470x; 3.9470x over previous
//
#include <hip/hip_runtime.h>

// 2-layer hetero SAGEConv, fully global-atomic-free:
//   radix partition by dst-bucket (LDS histograms) -> per-bucket local CSR
//   (LDS scan/rank) -> wave-per-node gather-mean -> two fused tile-GEMMs
//   with in-tile second stage (@Wl2 var path, @Wr2+bl2 config path).
//  - (msum/cnt)@W == (msum@W)/cnt
//  - h_var and h_config never materialized in global memory.
//  - Fb LDS uses a (col4 + row/4)&15 rotate swizzle: k-strided writes
//    conflict-free; k-loop reads are quarter-wave broadcasts.
//  - REGALLOC LESSONS: (r6) don't merge two unrolled GEMM bodies in one
//    kernel; (r7) don't FULLY unroll the 80/128-step k-loops — full unroll
//    let the scheduler pipeline all LDS loads -> 256 VGPR + HBM spill
//    traffic. Flat k-loop with partial `#pragma unroll 4` (round-5 style)
//    keeps live ranges bounded (88 VGPR).
//  - to_dense_batch is an identity reshape (batch = arange(NC)//K).

#define CHUNK 4096      // edges per partition block
#define EPT 16          // edges per thread (CHUNK/256)
#define MAXBINS 1024

// ---- partition phase 1: counts[bin][block], no global atomics ----
__global__ __launch_bounds__(256) void part_count2_kernel(
    const int* __restrict__ dstC, const int* __restrict__ dstV, int E, int nblocks,
    int nbinsC, int nbinsV, int* __restrict__ countsC, int* __restrict__ countsV) {
    const int* dst; int shift, nbins; int* counts; int b;
    if (blockIdx.x < (unsigned)nblocks) { dst = dstC; shift = 6; nbins = nbinsC; counts = countsC; b = blockIdx.x; }
    else { dst = dstV; shift = 7; nbins = nbinsV; counts = countsV; b = blockIdx.x - nblocks; }
    __shared__ int hist[MAXBINS];
    int t = threadIdx.x;
    for (int j = t; j < nbins; j += 256) hist[j] = 0;
    __syncthreads();
    int base = b * CHUNK;
#pragma unroll
    for (int j = 0; j < EPT; ++j) {
        int e = base + j * 256 + t;
        if (e < E) atomicAdd(&hist[dst[e] >> shift], 1);
    }
    __syncthreads();
    for (int j = t; j < nbins; j += 256) counts[(size_t)j * nblocks + b] = hist[j];
}

// ---- phase 2a: per-bin exclusive prefix over blocks; binTot ----
__global__ __launch_bounds__(256) void part_rowscan2_kernel(
    int* __restrict__ countsC, int nbinsC, int* __restrict__ binTotC,
    int* __restrict__ countsV, int* __restrict__ binTotV, int nblocks) {
    int* counts; int* binTot; int bin;
    if (blockIdx.x < (unsigned)nbinsC) { counts = countsC; binTot = binTotC; bin = blockIdx.x; }
    else { counts = countsV; binTot = binTotV; bin = blockIdx.x - nbinsC; }
    __shared__ int s[256];
    int t = threadIdx.x;
    int v = (t < nblocks) ? counts[(size_t)bin * nblocks + t] : 0;
    s[t] = v; __syncthreads();
    for (int o = 1; o < 256; o <<= 1) {
        int add = (t >= o) ? s[t - o] : 0; __syncthreads();
        s[t] += add; __syncthreads();
    }
    if (t < nblocks) counts[(size_t)bin * nblocks + t] = s[t] - v;
    if (t == nblocks - 1) binTot[bin] = s[t];
}

// ---- phase 2b: exclusive prefix over bins ----
__global__ __launch_bounds__(256) void part_binscan2_kernel(
    const int* __restrict__ binTotC, int nbinsC, int* __restrict__ binBaseC,
    const int* __restrict__ binTotV, int nbinsV, int* __restrict__ binBaseV) {
    const int* binTot; int nbins; int* binBase;
    if (blockIdx.x == 0) { binTot = binTotC; nbins = nbinsC; binBase = binBaseC; }
    else { binTot = binTotV; nbins = nbinsV; binBase = binBaseV; }
    __shared__ int s[256];
    __shared__ int carry;
    int t = threadIdx.x;
    if (t == 0) carry = 0;
    __syncthreads();
    for (int c0 = 0; c0 < nbins; c0 += 256) {
        int v = (c0 + t < nbins) ? binTot[c0 + t] : 0;
        s[t] = v; __syncthreads();
        for (int o = 1; o < 256; o <<= 1) {
            int add = (t >= o) ? s[t - o] : 0; __syncthreads();
            s[t] += add; __syncthreads();
        }
        if (c0 + t < nbins) binBase[c0 + t] = carry + s[t] - v;
        __syncthreads();
        if (t == 255) carry += s[255];
        __syncthreads();
    }
    if (t == 0) binBase[nbins] = carry;
}

// ---- phase 3: scatter packed (src<<shift)|local to deterministic slots ----
__global__ __launch_bounds__(256) void part_scatter2_kernel(
    const int* __restrict__ srcC, const int* __restrict__ dstC,
    const int* __restrict__ srcV, const int* __restrict__ dstV, int E, int nblocks,
    int nbinsC, const int* __restrict__ countsC, const int* __restrict__ binBaseC,
    int* __restrict__ ebufC,
    int nbinsV, const int* __restrict__ countsV, const int* __restrict__ binBaseV,
    int* __restrict__ ebufV) {
    const int *src, *dst, *counts, *binBase; int* ebuf; int shift, mask, nbins; int b;
    if (blockIdx.x < (unsigned)nblocks) {
        src = srcC; dst = dstC; counts = countsC; binBase = binBaseC; ebuf = ebufC;
        shift = 6; mask = 63; nbins = nbinsC; b = blockIdx.x;
    } else {
        src = srcV; dst = dstV; counts = countsV; binBase = binBaseV; ebuf = ebufV;
        shift = 7; mask = 127; nbins = nbinsV; b = blockIdx.x - nblocks;
    }
    __shared__ int hist[MAXBINS];
    int t = threadIdx.x;
    for (int j = t; j < nbins; j += 256) hist[j] = 0;
    __syncthreads();
    int base = b * CHUNK;
#pragma unroll
    for (int j = 0; j < EPT; ++j) {
        int e = base + j * 256 + t;
        if (e < E) {
            int d = dst[e];
            int bin = d >> shift;
            int rank = atomicAdd(&hist[bin], 1);
            int slot = binBase[bin] + counts[(size_t)bin * nblocks + b] + rank;
            ebuf[slot] = (src[e] << shift) | (d & mask);
        }
    }
}

// ---- phase 4: per-bucket local CSR (LDS only): ebuf2 per-node-ordered + off ----
__global__ __launch_bounds__(256) void csr2_kernel(
    int nbinsC, const int* __restrict__ binBaseC, const int* __restrict__ ebufC,
    int* __restrict__ ebufC2, int* __restrict__ offC, int nC,
    const int* __restrict__ binBaseV, const int* __restrict__ ebufV,
    int* __restrict__ ebufV2, int* __restrict__ offV, int nV, int E) {
    __shared__ int hist[128];
    __shared__ int cur[128];
    __shared__ int s[256];
    int t = threadIdx.x;
    const int *binBase, *eb1; int *eb2, *off; int n, shift, bin;
    if (blockIdx.x < (unsigned)nbinsC) {
        bin = blockIdx.x; binBase = binBaseC; eb1 = ebufC; eb2 = ebufC2; off = offC; n = nC; shift = 6;
    } else {
        bin = blockIdx.x - nbinsC; binBase = binBaseV; eb1 = ebufV; eb2 = ebufV2; off = offV; n = nV; shift = 7;
    }
    int mask = (1 << shift) - 1, nloc = 1 << shift;
    if (blockIdx.x == 0 && t == 0) { offC[nC] = E; offV[nV] = E; }
    int e0 = binBase[bin], e1 = binBase[bin + 1];
    if (t < nloc) { hist[t] = 0; cur[t] = 0; }
    __syncthreads();
    for (int e = e0 + t; e < e1; e += 256) atomicAdd(&hist[eb1[e] & mask], 1);
    __syncthreads();
    int v = (t < nloc) ? hist[t] : 0;
    s[t] = v; __syncthreads();
    for (int o = 1; o < 256; o <<= 1) {
        int add = (t >= o) ? s[t - o] : 0; __syncthreads();
        s[t] += add; __syncthreads();
    }
    if (t < nloc) {
        int node = (bin << shift) + t;
        if (node < n) off[node] = e0 + s[t] - v;
        hist[t] = s[t] - v;   // reuse as local exclusive offset
    }
    __syncthreads();
    for (int e = e0 + t; e < e1; e += 256) {
        int w = eb1[e];
        int local = w & mask;
        int r = atomicAdd(&cur[local], 1);
        eb2[e0 + hist[local] + r] = w >> shift;
    }
}

// ---- wave-per-node gather-mean bodies ----
__device__ __forceinline__ void gather64_body(
    const int* __restrict__ off, const int* __restrict__ eb,
    const float* __restrict__ X, float* __restrict__ M,
    const float* __restrict__ P, float* __restrict__ out,
    int n, int b, int nblocks) {
    int lane = threadIdx.x & 63, wid = threadIdx.x >> 6;
    int nw = nblocks * 4;
    for (int i = b * 4 + wid; i < n; i += nw) {
        int e0 = off[i], e1 = off[i + 1];
        int deg = e1 - e0;
        float acc = 0.f;
        for (int j0 = 0; j0 < deg; j0 += 64) {
            int m = min(deg - j0, 64);
            int idx = 0;
            if (lane < m) idx = eb[e0 + j0 + lane];
            int j = 0;
            for (; j + 4 <= m; j += 4) {
                int s0 = __shfl(idx, j);
                int s1 = __shfl(idx, j + 1);
                int s2 = __shfl(idx, j + 2);
                int s3 = __shfl(idx, j + 3);
                acc += X[(size_t)s0 * 64 + lane];
                acc += X[(size_t)s1 * 64 + lane];
                acc += X[(size_t)s2 * 64 + lane];
                acc += X[(size_t)s3 * 64 + lane];
            }
            for (; j < m; ++j) {
                int s = __shfl(idx, j);
                acc += X[(size_t)s * 64 + lane];
            }
        }
        float r = acc / fmaxf((float)deg, 1.0f);
        if (out) out[(size_t)i * 64 + lane] = r + P[(size_t)i * 64 + lane];
        else     M[(size_t)i * 64 + lane] = r;
    }
}

__device__ __forceinline__ void gather16_body(
    const int* __restrict__ off, const int* __restrict__ eb,
    const float* __restrict__ X, float* __restrict__ M, int n, int b, int nblocks) {
    int lane = threadIdx.x & 63, wid = threadIdx.x >> 6;
    int dlane = lane & 15, eg = lane >> 4;
    int nw = nblocks * 4;
    for (int i = b * 4 + wid; i < n; i += nw) {
        int e0 = off[i], e1 = off[i + 1];
        int deg = e1 - e0;
        float acc = 0.f;
        for (int j0 = 0; j0 < deg; j0 += 64) {
            int m = min(deg - j0, 64);
            int idx = 0;
            if (lane < m) idx = eb[e0 + j0 + lane];
            for (int j = eg; j < m; j += 4) {
                int s = __shfl(idx, j);
                acc += X[(size_t)s * 16 + dlane];
            }
        }
        acc += __shfl_xor(acc, 16);
        acc += __shfl_xor(acc, 32);
        if (lane < 16) M[(size_t)i * 16 + lane] = acc / fmaxf((float)deg, 1.0f);
    }
}

// combined layer-1 gathers (independent)
__global__ __launch_bounds__(256) void gather2_kernel(
    const int* __restrict__ offC, const int* __restrict__ ebC,
    const float* __restrict__ Xc, float* __restrict__ Mc, int nC, int gbC,
    const int* __restrict__ offV, const int* __restrict__ ebV,
    const float* __restrict__ Xv, float* __restrict__ Mv, int nV, int gbV) {
    if (blockIdx.x < (unsigned)gbC)
        gather64_body(offC, ebC, Xc, Mc, nullptr, nullptr, nC, blockIdx.x, gbC);
    else
        gather16_body(offV, ebV, Xv, Mv, nV, blockIdx.x - gbC, gbV);
}

// layer-2 gather fused with final add: out = mean(hv2) + OCp
__global__ __launch_bounds__(256) void gather64_add_kernel(
    const int* __restrict__ off, const int* __restrict__ eb,
    const float* __restrict__ X, const float* __restrict__ P,
    float* __restrict__ out, int n) {
    gather64_body(off, eb, X, nullptr, P, out, n, blockIdx.x, gridDim.x);
}

// ---------------- fused tile GEMM (swizzled LDS, bounded unroll) ----------------
// Fb layout: 128 rows x 68 floats; float4 (row, col4) stored at
//   col4' = (col4 + (row>>2)) & 15  -> k-strided writes conflict-free,
//   k-loop reads stay quarter-wave broadcasts. Every access touches rows
//   4m..4m+3 with constant row>>2, so the swizzle index is uniform per access.
template<int D, int ROW0>
__device__ __forceinline__ void stageF_swz(const float* __restrict__ A, float* __restrict__ Fb,
                                           int i0, int n, int t) {
    const int Q = D / 4;          // float4s per input row
    const int NPP = 256 / Q;      // nodes per pass
#pragma unroll
    for (int p = 0; p < 64 / NPP; ++p) {
        int nn = t / Q + p * NPP;      // node 0..63
        int k4 = t % Q;                // input float4 index
        int node = i0 + nn;
        float4 v = make_float4(0.f, 0.f, 0.f, 0.f);
        if (node < n) v = ((const float4*)A)[(size_t)node * Q + k4];
        int cs = (((nn >> 2) + (ROW0 >> 2) + k4) & 15) * 4 + (nn & 3);
        float* q = Fb + (ROW0 + 4 * k4) * 68 + cs;
        q[0 * 68] = v.x; q[1 * 68] = v.y; q[2 * 68] = v.z; q[3 * 68] = v.w;
    }
}

// stage1: H[64n][128] = relu(M[:,D1]@Wl + X[:,D2]@Wr + bias) (kept in LDS)
// stage2: O[64n][64]  = H @ W2 (+ bias2 if HASB2)
template<int D1, int D2, bool HASB2>
__global__ __launch_bounds__(256) void gemm_swz_kernel(
    const float* __restrict__ M, const float* __restrict__ X,
    const float* __restrict__ Wl, const float* __restrict__ Wr,
    const float* __restrict__ bias, const float* __restrict__ W2,
    const float* __restrict__ bias2, float* __restrict__ O, int n) {
    __shared__ float Fb[128 * 68];
    __shared__ float Wb[80 * 128];
    int t = threadIdx.x;
    int i0 = blockIdx.x * 64;
    {
        const float4* wl4 = (const float4*)Wl;
        const float4* wr4 = (const float4*)Wr;
        float4* wb4 = (float4*)Wb;
        for (int j = t; j < D1 * 32; j += 256) wb4[j] = wl4[j];
        for (int j = t; j < D2 * 32; j += 256) wb4[D1 * 32 + j] = wr4[j];
    }
    stageF_swz<D1, 0>(M, Fb, i0, n, t);
    stageF_swz<D2, D1>(X, Fb, i0, n, t);
    __syncthreads();
    int tc = t & 15, tn = t >> 4;
    int c0 = tc * 4, n0 = tn * 4;
    float acc[4][8];
#pragma unroll
    for (int j = 0; j < 4; ++j)
#pragma unroll
        for (int jj = 0; jj < 8; ++jj) acc[j][jj] = 0.f;
#pragma unroll 4
    for (int k = 0; k < D1 + D2; ++k) {
        int sw = ((tn + (k >> 2)) & 15) * 4;
        float4 f  = *(const float4*)&Fb[k * 68 + sw];
        float4 wa = *(const float4*)&Wb[k * 128 + c0];
        float4 wc = *(const float4*)&Wb[k * 128 + 64 + c0];
        float ff[4] = {f.x, f.y, f.z, f.w};
        float va[4] = {wa.x, wa.y, wa.z, wa.w};
        float vb[4] = {wc.x, wc.y, wc.z, wc.w};
#pragma unroll
        for (int j = 0; j < 4; ++j)
#pragma unroll
            for (int jj = 0; jj < 4; ++jj) {
                acc[j][jj]     += ff[j] * va[jj];
                acc[j][4 + jj] += ff[j] * vb[jj];
            }
    }
    __syncthreads();   // all stage-1 reads of Fb/Wb done
    {
        float4 blo = ((const float4*)bias)[tc];
        float4 bhi = ((const float4*)bias)[16 + tc];
        float bl[8] = {blo.x, blo.y, blo.z, blo.w, bhi.x, bhi.y, bhi.z, bhi.w};
        int sw1 = ((tn + tc) & 15) * 4;        // rows c0+jj:    row>>2 = tc
        int sw2 = ((tn + 16 + tc) & 15) * 4;   // rows 64+c0+jj: row>>2 = 16+tc
#pragma unroll
        for (int jj = 0; jj < 4; ++jj) {
            float4 h1, h2;
            h1.x = fmaxf(acc[0][jj] + bl[jj], 0.f);
            h1.y = fmaxf(acc[1][jj] + bl[jj], 0.f);
            h1.z = fmaxf(acc[2][jj] + bl[jj], 0.f);
            h1.w = fmaxf(acc[3][jj] + bl[jj], 0.f);
            h2.x = fmaxf(acc[0][4 + jj] + bl[4 + jj], 0.f);
            h2.y = fmaxf(acc[1][4 + jj] + bl[4 + jj], 0.f);
            h2.z = fmaxf(acc[2][4 + jj] + bl[4 + jj], 0.f);
            h2.w = fmaxf(acc[3][4 + jj] + bl[4 + jj], 0.f);
            // H row = c0+jj (and 64+c0+jj), col4 = tn
            *(float4*)&Fb[(c0 + jj) * 68 + sw1] = h1;
            *(float4*)&Fb[(64 + c0 + jj) * 68 + sw2] = h2;
        }
        const float4* w24 = (const float4*)W2;
        float4* wb4 = (float4*)Wb;
        for (int j = t; j < 128 * 16; j += 256) wb4[j] = w24[j];
    }
    __syncthreads();
    float a2[4][4];
#pragma unroll
    for (int j = 0; j < 4; ++j)
#pragma unroll
        for (int jj = 0; jj < 4; ++jj) a2[j][jj] = 0.f;
#pragma unroll 4
    for (int k = 0; k < 128; ++k) {
        int sw = ((tn + (k >> 2)) & 15) * 4;
        float4 h = *(const float4*)&Fb[k * 68 + sw];
        float4 w = *(const float4*)&Wb[k * 64 + c0];
        float hh[4] = {h.x, h.y, h.z, h.w};
        float ww[4] = {w.x, w.y, w.z, w.w};
#pragma unroll
        for (int j = 0; j < 4; ++j)
#pragma unroll
            for (int jj = 0; jj < 4; ++jj) a2[j][jj] += hh[j] * ww[jj];
    }
    float4 b2 = HASB2 ? ((const float4*)bias2)[tc] : make_float4(0.f, 0.f, 0.f, 0.f);
#pragma unroll
    for (int j = 0; j < 4; ++j) {
        int node = i0 + n0 + j;
        if (node < n) {
            float4 o = {a2[j][0] + b2.x, a2[j][1] + b2.y, a2[j][2] + b2.z, a2[j][3] + b2.w};
            ((float4*)O)[(size_t)node * 16 + tc] = o;
        }
    }
}

extern "C" void kernel_launch(void* const* d_in, const int* in_sizes, int n_in,
                              void* d_out, int out_size, void* d_ws, size_t ws_size,
                              hipStream_t stream) {
    const float* x_var    = (const float*)d_in[0];
    const float* x_config = (const float*)d_in[1];
    const int* src_v2c = (const int*)d_in[2];
    const int* dst_v2c = (const int*)d_in[3];
    const int* src_c2v = (const int*)d_in[4];
    const int* dst_c2v = (const int*)d_in[5];
    const float* Wl1_v2c = (const float*)d_in[7];
    const float* bl1_v2c = (const float*)d_in[8];
    const float* Wr1_v2c = (const float*)d_in[9];
    const float* Wl1_c2v = (const float*)d_in[10];
    const float* bl1_c2v = (const float*)d_in[11];
    const float* Wr1_c2v = (const float*)d_in[12];
    const float* Wl2 = (const float*)d_in[13];
    const float* bl2 = (const float*)d_in[14];
    const float* Wr2 = (const float*)d_in[15];
    float* out = (float*)d_out;

    int NV = in_sizes[0] / 64;
    int NC = in_sizes[1] / 16;
    int E  = in_sizes[2];

    int nblocks = (E + CHUNK - 1) / CHUNK;          // <=256 for rowscan
    int nbins_c = (NC + 63) >> 6;                   // 64 config nodes / bucket
    int nbins_v = (NV + 127) >> 7;                  // 128 var nodes / bucket

    char* p = (char*)d_ws;
    float* Mc  = (float*)p; p += (size_t)NC * 64 * 4;
    float* Mv  = (float*)p; p += (size_t)NV * 16 * 4;
    float* OCp = (float*)p; p += (size_t)NC * 64 * 4;   // h_config@Wr2 + bl2
    float* hv2 = (float*)p; p += (size_t)NV * 64 * 4;   // h_var@Wl2
    int* countsC = (int*)p; p += (size_t)nbins_c * nblocks * 4;
    int* countsV = (int*)p; p += (size_t)nbins_v * nblocks * 4;
    int* binTotC = (int*)p; p += (size_t)nbins_c * 4;
    int* binTotV = (int*)p; p += (size_t)nbins_v * 4;
    int* binBaseC = (int*)p; p += (size_t)(nbins_c + 1) * 4;
    int* binBaseV = (int*)p; p += (size_t)(nbins_v + 1) * 4;
    int* offC = (int*)p; p += (size_t)(NC + 1) * 4;
    int* offV = (int*)p; p += (size_t)(NV + 1) * 4;
    int* ebufC  = (int*)p; p += (size_t)E * 4;
    int* ebufV  = (int*)p; p += (size_t)E * 4;
    int* ebufC2 = (int*)p; p += (size_t)E * 4;
    int* ebufV2 = (int*)p; p += (size_t)E * 4;

    part_count2_kernel<<<2 * nblocks, 256, 0, stream>>>(
        dst_v2c, dst_c2v, E, nblocks, nbins_c, nbins_v, countsC, countsV);
    part_rowscan2_kernel<<<nbins_c + nbins_v, 256, 0, stream>>>(
        countsC, nbins_c, binTotC, countsV, binTotV, nblocks);
    part_binscan2_kernel<<<2, 256, 0, stream>>>(
        binTotC, nbins_c, binBaseC, binTotV, nbins_v, binBaseV);
    part_scatter2_kernel<<<2 * nblocks, 256, 0, stream>>>(
        src_v2c, dst_v2c, src_c2v, dst_c2v, E, nblocks,
        nbins_c, countsC, binBaseC, ebufC,
        nbins_v, countsV, binBaseV, ebufV);
    csr2_kernel<<<nbins_c + nbins_v, 256, 0, stream>>>(
        nbins_c, binBaseC, ebufC, ebufC2, offC, NC,
        binBaseV, ebufV, ebufV2, offV, NV, E);

    int gbC = (NC + 3) / 4, gbV = (NV + 3) / 4;
    gather2_kernel<<<gbC + gbV, 256, 0, stream>>>(
        offC, ebufC2, x_var, Mc, NC, gbC,
        offV, ebufV2, x_config, Mv, NV, gbV);

    gemm_swz_kernel<64, 16, true><<<(NC + 63) / 64, 256, 0, stream>>>(
        Mc, x_config, Wl1_v2c, Wr1_v2c, bl1_v2c, Wr2, bl2, OCp, NC);
    gemm_swz_kernel<16, 64, false><<<(NV + 63) / 64, 256, 0, stream>>>(
        Mv, x_var, Wl1_c2v, Wr1_c2v, bl1_c2v, Wl2, nullptr, hv2, NV);

    gather64_add_kernel<<<gbC, 256, 0, stream>>>(offC, ebufC2, hv2, OCp, out, NC);
}